// Round 10
// baseline (338.503 us; speedup 1.0000x reference)
//
#include <hip/hip_runtime.h>
#include <hip/hip_bf16.h>

#define BATCH 16
#define SEQ 8192
#define CH 32
#define NB 24

typedef __attribute__((ext_vector_type(8))) short short8;
typedef __attribute__((ext_vector_type(4))) float f32x4;

#define LROW 36  // fp32 LDS row stride (144 B: 16B-aligned, spreads 16B-groups over all 8)

__device__ __forceinline__ unsigned short f2bf(float x) {
    __hip_bfloat16 b = __float2bfloat16(x);   // RNE
    unsigned short u;
    __builtin_memcpy(&u, &b, 2);
    return u;
}
__device__ __forceinline__ float bf2f(unsigned short h) {
    return __uint_as_float(((unsigned int)h) << 16);
}
__device__ __forceinline__ float rcp_fast(float x) { return __builtin_amdgcn_rcpf(x); }

// tanh(f)*sigmoid(g) with a single reciprocal
__device__ __forceinline__ float gate_fn(float f, float g) {
    float ef = __expf(-2.0f * fabsf(f));
    float eg = __expf(-g);
    float num = 1.0f - ef;
    float den = (1.0f + ef) * (1.0f + eg);
    return copysignf(num * rcp_fast(den), f);
}

__device__ __forceinline__ void split2(float v, unsigned short& h, unsigned short& l) {
    h = f2bf(v);
    l = f2bf(v - bf2f(h));
}

// ============ prep (256 thr/block): split weights to bf16 hi/lo in MFMA frag order.
// r10: conv OUTPUT rows are sigma-permuted so the gated C-layout IS the skip B-layout:
//   tile rt (0,1 = f-halves; 2,3 = g-halves), frag row p -> channel 8*(p>>2)+4*(rt&1)+(p&3)
// After gating, lane (p,h4) then holds channels 8h4+j at j=4rt+r — no LDS bounce needed.
// W1 A-frags (k = channel, natural order) and skip biases unchanged. Zeros pooled.
__global__ __launch_bounds__(256) void k_prep(const float* __restrict__ Wd,
                                              const float* __restrict__ bd,
                                              const float* __restrict__ W1,
                                              const float* __restrict__ b1,
                                              unsigned short* __restrict__ stream,
                                              float* __restrict__ pooled) {
    int i = blockIdx.x;
    int tid = threadIdx.x;
    int l = tid & 63, q4 = tid >> 6;
    int p = l & 15, h4 = l >> 4;
    const float* wd  = Wd + (size_t)i * 64 * 64;
    const float* w1  = W1 + (size_t)i * 1024;
    const float* bdp = bd + (size_t)i * 64;
    const float* b1p = b1 + (size_t)i * 32;
    unsigned short* out = stream + (size_t)i * (28672 / 2);

    for (int g = blockIdx.x * 256 + tid; g < BATCH * CH * 4; g += NB * 256)
        pooled[g] = 0.0f;

    // conv A-frags: quarter q4 handles tile rt = q4
    {
        int rt = q4;
        int is_g = (rt >= 2) ? 32 : 0;
        int ch = 8 * (p >> 2) + 4 * (rt & 1) + (p & 3);     // sigma(rt, p)
        int row = ch + is_g;
        for (int q = 0; q < 2; ++q) {
            int slot = rt * 2 + q;
            for (int j = 0; j < 8; ++j) {
                int k = 32 * q + 8 * h4 + j;
                int c = k & 31, tap = k >> 5;
                float w = wd[row * 64 + c * 2 + tap];
                unsigned short hi = f2bf(w);
                out[(size_t)slot * 512 + l * 8 + j] = hi;
                out[(size_t)(8 + slot) * 512 + l * 8 + j] = f2bf(w - bf2f(hi));
            }
        }
    }
    // skip A-frags (natural row order): quarters 0,1
    if (q4 < 2) {
        int rt2 = q4;
        for (int j = 0; j < 8; ++j) {
            int o = 16 * rt2 + p, c = 8 * h4 + j;
            float w = w1[o * 32 + c];
            unsigned short hi = f2bf(w);
            out[(size_t)(16 + rt2) * 512 + l * 8 + j] = hi;
            out[(size_t)(18 + rt2) * 512 + l * 8 + j] = f2bf(w - bf2f(hi));
        }
    }
    float* outf = (float*)stream + (size_t)i * (28672 / 4);
    // conv biases, sigma-permuted rows (C reg r at lane h4 = channel 8h4+4*(rt&1)+r)
    if (q4 == 2) {
        for (int rt = 0; rt < 4; ++rt) {
            int is_g = (rt >= 2) ? 32 : 0;
            for (int r = 0; r < 4; ++r)
                outf[(size_t)(20 + rt) * 256 + l * 4 + r] =
                    bdp[8 * h4 + 4 * (rt & 1) + r + is_g];
        }
    }
    // skip biases (natural order)
    if (q4 == 3) {
        for (int rt2 = 0; rt2 < 2; ++rt2)
            for (int r = 0; r < 4; ++r)
                outf[(size_t)(24 + rt2) * 256 + l * 4 + r] = b1p[16 * rt2 + 4 * h4 + r];
    }
}

// ============ fused 8-layer stack, h resident in LDS as fp32 (r8 structure).
// r10: no gbuf, no fence — gated values feed the skip MFMA directly from registers
// (sigma-permuted conv rows). Two-phase per layer (read-all -> sync -> write-all).
// stack0 builds h0 from x in-LDS; stack2 runs the finale epilogue in-LDS.
// Causal gate on GLOBAL source position (r5 fix).
__global__ __launch_bounds__(512, 2) void k_stack(
        const float* __restrict__ hin,
        float* __restrict__ hout,
        const float* __restrict__ x,
        const float* __restrict__ W0,
        const float* __restrict__ b0,
        const float* __restrict__ Wf,
        const float* __restrict__ bf,
        float* __restrict__ pooled,
        const unsigned short* __restrict__ wstream,
        int stack) {
    __shared__ __align__(16) float lh[768 * LROW];                    // 110,592 B
    __shared__ float red[8 * CH];                                     // 1,024 B

    int tid = threadIdx.x;
    int lane = tid & 63, wave = tid >> 6;
    int p = lane & 15, h4 = lane >> 4;
    int bb = blockIdx.x >> 4;
    int T0 = (blockIdx.x & 15) * 512;
    bool first = (stack == 0);
    bool last  = (stack == 2);

    const float* pin = hin + (size_t)bb * SEQ * CH;
    float* pout = hout + (size_t)bb * SEQ * CH;
    const float* px = x + (size_t)bb * SEQ;

    const f32x4 zero4 = {0.0f, 0.0f, 0.0f, 0.0f};

    // ---- load tile [T0-256, T0+512) into LDS (zeros for t<0)
    if (first) {
        for (int i = tid; i < 768; i += 512) {
            int t = T0 - 256 + i;
            float* dst = &lh[i * LROW];
            if (t >= 0) {
                float xt = px[t];
                float xm = (t > 0) ? px[t - 1] : 0.0f;
                __align__(16) float hv[CH];
#pragma unroll
                for (int c = 0; c < CH; ++c)
                    hv[c] = W0[c * 2] * xm + W0[c * 2 + 1] * xt + b0[c];
#pragma unroll
                for (int k = 0; k < 8; ++k)
                    *(f32x4*)(dst + 4 * k) = *(const f32x4*)(hv + 4 * k);
            } else {
#pragma unroll
                for (int k = 0; k < 8; ++k)
                    *(f32x4*)(dst + 4 * k) = zero4;
            }
        }
    } else {
        for (int i = tid; i < 768; i += 512) {
            int t = T0 - 256 + i;
            float* dst = &lh[i * LROW];
            if (t >= 0) {
                const float* src = pin + (size_t)t * CH;
#pragma unroll
                for (int k = 0; k < 8; ++k)
                    *(f32x4*)(dst + 4 * k) = *(const f32x4*)(src + 4 * k);
            } else {
#pragma unroll
                for (int k = 0; k < 8; ++k)
                    *(f32x4*)(dst + 4 * k) = zero4;
            }
        }
    }
    __syncthreads();

#pragma unroll 1
    for (int l = 0; l < 8; ++l) {
        int dil = 1 << l;
        const unsigned short* frag = wstream + (size_t)(8 * stack + l) * 14336;
        const short8* fs = (const short8*)frag;
        short8 Ah[4][2], Al[4][2], Sh[2], Sl[2];
#pragma unroll
        for (int rt = 0; rt < 4; ++rt)
#pragma unroll
            for (int q = 0; q < 2; ++q) {
                Ah[rt][q] = fs[(rt * 2 + q) * 64 + lane];
                Al[rt][q] = fs[(8 + rt * 2 + q) * 64 + lane];
            }
#pragma unroll
        for (int rt2 = 0; rt2 < 2; ++rt2) {
            Sh[rt2] = fs[(16 + rt2) * 64 + lane];
            Sl[rt2] = fs[(18 + rt2) * 64 + lane];
        }
        const f32x4* ff = (const f32x4*)frag;
        f32x4 bFG[4], bS[2];
#pragma unroll
        for (int rt = 0; rt < 4; ++rt) bFG[rt] = ff[(20 + rt) * 64 + lane];
#pragma unroll
        for (int rt2 = 0; rt2 < 2; ++rt2) bS[rt2] = ff[(24 + rt2) * 64 + lane];

        f32x4 hnew[6][2];

        // ---- phase 1: read OLD h, compute new h into registers (all register-local
        // after the conv reads; no LDS bounce, no waitcnt fences)
#pragma unroll
        for (int s6 = 0; s6 < 6; ++s6) {
            int tpos = wave * 96 + s6 * 16 + p;
            int tq = tpos - dil;
            bool ok = (T0 - 256 + tq >= 0);   // causal gate on GLOBAL source pos
            int tqc = (tq > 0) ? tq : 0;

            const float* r1 = &lh[tpos * LROW + 8 * h4];
            const float* r0 = &lh[tqc * LROW + 8 * h4];
            f32x4 v1a = *(const f32x4*)r1, v1b = *(const f32x4*)(r1 + 4);
            f32x4 v0a = *(const f32x4*)r0, v0b = *(const f32x4*)(r0 + 4);
            if (!ok) { v0a = zero4; v0b = zero4; }
            short8 bh1, bl1, bh0, bl0;
#pragma unroll
            for (int j = 0; j < 4; ++j) {
                unsigned short hh, ll;
                split2(v1a[j], hh, ll); bh1[j] = (short)hh; bl1[j] = (short)ll;
                split2(v1b[j], hh, ll); bh1[4 + j] = (short)hh; bl1[4 + j] = (short)ll;
                split2(v0a[j], hh, ll); bh0[j] = (short)hh; bl0[j] = (short)ll;
                split2(v0b[j], hh, ll); bh0[4 + j] = (short)hh; bl0[4 + j] = (short)ll;
            }

            f32x4 acc[4];
#pragma unroll
            for (int rt = 0; rt < 4; ++rt) {
                f32x4 a = bFG[rt];
                a = __builtin_amdgcn_mfma_f32_16x16x32_bf16(Ah[rt][0], bh0, a, 0, 0, 0);
                a = __builtin_amdgcn_mfma_f32_16x16x32_bf16(Ah[rt][1], bh1, a, 0, 0, 0);
                a = __builtin_amdgcn_mfma_f32_16x16x32_bf16(Ah[rt][0], bl0, a, 0, 0, 0);
                a = __builtin_amdgcn_mfma_f32_16x16x32_bf16(Ah[rt][1], bl1, a, 0, 0, 0);
                a = __builtin_amdgcn_mfma_f32_16x16x32_bf16(Al[rt][0], bh0, a, 0, 0, 0);
                a = __builtin_amdgcn_mfma_f32_16x16x32_bf16(Al[rt][1], bh1, a, 0, 0, 0);
                acc[rt] = a;
            }

            // gate -> split -> skip B-frag DIRECTLY in registers (sigma permutation:
            // lane (p,h4) slot j=4rt+r holds channel 8h4+j)
            short8 Bgh, Bgl;
#pragma unroll
            for (int rt = 0; rt < 2; ++rt)
#pragma unroll
                for (int r = 0; r < 4; ++r) {
                    float gated = gate_fn(acc[rt][r], acc[rt + 2][r]);
                    unsigned short hh, ll;
                    split2(gated, hh, ll);
                    Bgh[4 * rt + r] = (short)hh;
                    Bgl[4 * rt + r] = (short)ll;
                }

            f32x4 sacc[2];
#pragma unroll
            for (int rt2 = 0; rt2 < 2; ++rt2) {
                f32x4 a = bS[rt2];
                a = __builtin_amdgcn_mfma_f32_16x16x32_bf16(Sh[rt2], Bgh, a, 0, 0, 0);
                a = __builtin_amdgcn_mfma_f32_16x16x32_bf16(Sh[rt2], Bgl, a, 0, 0, 0);
                a = __builtin_amdgcn_mfma_f32_16x16x32_bf16(Sl[rt2], Bgh, a, 0, 0, 0);
                sacc[rt2] = a;
            }

            // residual: hnew = h(fp32) + skip   (C-layout: ch = 16rt2+4h4+r)
#pragma unroll
            for (int rt2 = 0; rt2 < 2; ++rt2) {
                f32x4 hold = *(const f32x4*)&lh[tpos * LROW + 16 * rt2 + 4 * h4];
                hnew[s6][rt2] = hold + sacc[rt2];
            }
        }
        __syncthreads();

        // ---- phase 2: write new h (raw fp32)
#pragma unroll
        for (int s6 = 0; s6 < 6; ++s6) {
            int tpos = wave * 96 + s6 * 16 + p;
#pragma unroll
            for (int rt2 = 0; rt2 < 2; ++rt2)
                *(f32x4*)&lh[tpos * LROW + 16 * rt2 + 4 * h4] = hnew[s6][rt2];
        }
        __syncthreads();
    }

    if (!last) {
        // ---- store output region [T0, T0+512)
        int i = 256 + tid;
        int t = T0 + tid;
        const float* src = &lh[i * LROW];
        float* dst = pout + (size_t)t * CH;
#pragma unroll
        for (int k = 0; k < 8; ++k)
            *(f32x4*)(dst + 4 * k) = *(const f32x4*)(src + 4 * k);
    } else {
        // ---- fused finale: relu(h - h0(x)) -> Wf -> relu -> chunk-max -> atomicMax
        int i = 256 + tid;
        int t = T0 + tid;
        int q = (blockIdx.x & 15) >> 2;        // which L/4 quarter
        float xt = px[t];
        float xm = (t > 0) ? px[t - 1] : 0.0f;
        const float* src = &lh[i * LROW];

        float r[CH];
#pragma unroll
        for (int c = 0; c < CH; ++c) {
            float h0 = W0[c * 2] * xm + W0[c * 2 + 1] * xt + b0[c];
            r[c] = fmaxf(src[c] - h0, 0.0f);
        }
        float y[CH];
#pragma unroll 1
        for (int o = 0; o < CH; ++o) {
            const float* w = Wf + o * CH;
            float a0 = bf[o], a1 = 0.0f, a2 = 0.0f, a3 = 0.0f;
#pragma unroll
            for (int c = 0; c < CH; c += 4) {
                a0 += w[c + 0] * r[c + 0];
                a1 += w[c + 1] * r[c + 1];
                a2 += w[c + 2] * r[c + 2];
                a3 += w[c + 3] * r[c + 3];
            }
            y[o] = fmaxf((a0 + a1) + (a2 + a3), 0.0f);
        }
#pragma unroll
        for (int o = 0; o < CH; ++o) {
#pragma unroll
            for (int off = 32; off >= 1; off >>= 1)
                y[o] = fmaxf(y[o], __shfl_xor(y[o], off));
        }
        if (lane == 0) {
#pragma unroll
            for (int o = 0; o < CH; ++o) red[wave * CH + o] = y[o];
        }
        __syncthreads();
        if (tid < CH) {
            float m = red[tid];
#pragma unroll
            for (int w8 = 1; w8 < 8; ++w8) m = fmaxf(m, red[w8 * CH + tid]);
            atomicMax((unsigned int*)&pooled[bb * (CH * 4) + tid * 4 + q],
                      __float_as_uint(m));
        }
    }
}

// ============ final MLP
__global__ __launch_bounds__(1024) void k_final2(const float* __restrict__ pooled,
                                                 const float* __restrict__ fW1,
                                                 const float* __restrict__ fb1,
                                                 const float* __restrict__ fW2,
                                                 const float* __restrict__ fb2,
                                                 float* __restrict__ out) {
    __shared__ float y1[BATCH * 64];
    int tid = threadIdx.x;
    int b = tid >> 6, o = tid & 63;
    float acc = fb1[o];
#pragma unroll
    for (int j = 0; j < 128; ++j) acc += fW1[o * 128 + j] * pooled[b * 128 + j];
    y1[b * 64 + o] = fmaxf(acc, 0.0f);
    __syncthreads();
    if (tid < BATCH * 10) {
        int bb = tid / 10, o2 = tid % 10;
        float a2 = fb2[o2];
#pragma unroll
        for (int j = 0; j < 64; ++j) a2 += fW2[o2 * 64 + j] * y1[bb * 64 + j];
        out[bb * 10 + o2] = a2;
    }
}

extern "C" void kernel_launch(void* const* d_in, const int* in_sizes, int n_in,
                              void* d_out, int out_size, void* d_ws, size_t ws_size,
                              hipStream_t stream) {
    const float* x   = (const float*)d_in[0];
    const float* W0  = (const float*)d_in[1];
    const float* b0  = (const float*)d_in[2];
    const float* Wd  = (const float*)d_in[3];
    const float* bd  = (const float*)d_in[4];
    const float* W1  = (const float*)d_in[5];
    const float* b1  = (const float*)d_in[6];
    const float* Wf  = (const float*)d_in[7];
    const float* bf  = (const float*)d_in[8];
    const float* fW1 = (const float*)d_in[9];
    const float* fb1 = (const float*)d_in[10];
    const float* fW2 = (const float*)d_in[11];
    const float* fb2 = (const float*)d_in[12];
    float* out = (float*)d_out;

    const size_t HS = (size_t)BATCH * SEQ * CH;        // 4M floats = 16 MB
    float* bufA = (float*)d_ws;
    float* bufB = bufA + HS;
    unsigned short* wstream = (unsigned short*)(bufB + HS);   // 24 * 14336 shorts
    float* pooled = (float*)(wstream + (size_t)NB * 14336);

    k_prep<<<NB, 256, 0, stream>>>(Wd, bd, W1, b1, wstream, pooled);

    // stack 0: x -> B (h0 built in-LDS) ; stack 1: B -> A ; stack 2: A -> finale
    k_stack<<<256, 512, 0, stream>>>(bufA, bufB, x, W0, b0, Wf, bf, pooled, wstream, 0);
    k_stack<<<256, 512, 0, stream>>>(bufB, bufA, x, W0, b0, Wf, bf, pooled, wstream, 1);
    k_stack<<<256, 512, 0, stream>>>(bufA, bufA, x, W0, b0, Wf, bf, pooled, wstream, 2);

    k_final2<<<1, 1024, 0, stream>>>(pooled, fW1, fb1, fW2, fb2, out);
}